// Round 5
// baseline (189.265 us; speedup 1.0000x reference)
//
#include <hip/hip_runtime.h>

// SynesthesiaCentralOrchestrator: per-point Karcher mean of 4 unit quaternions,
// 10 fixed iterations (global convergence flag provably never fires in fp32).
// Quaternion stored as float4: .x=w, .y=x, .z=y, .w=z.
//
// R3: per-block partials instead of single-address atomicAdd (was ~800us drain).
// R4: log-map via dots only (tangent sum is linear in p_k); no per-iter renorm.
// R5: trans ops are ~32 issue-cy on gfx950 (1/16 rate) and were 60% of time.
//     12 -> 4 trans/iter:
//     (a) exp map: cos(theta), sin(theta)/theta as polynomials in theta^2
//         (even functions -> no sqrt/sin/cos/rcp at all; err <= 7e-6 on [0,pi^2])
//     (b) log scale: s(w) = 0.25*acos(w)/sqrt(1-w^2) via
//         s = (w>=0) ? F(|w|) : (pi/4)*rsqrt(1-w^2) - F(|w|),
//         F = deg-9 series of 0.25*theta/sin(theta) in v=1-|w| (err <= 1.3e-4);
//         uses the identity 0.25*acos(a)*R = F(a) with R*R*(1-a^2) = 1.

#define NPTS (2048 * 2048)
#define NBLK (NPTS / 256)   // 16384 blocks; ws usage = 64 KB

__device__ __forceinline__ float frsq(float x) { return __builtin_amdgcn_rsqf(x); }

__device__ __forceinline__ float4 qnorm_fast(const float4 q) {
    float inv = frsq(fmaf(q.x, q.x, fmaf(q.y, q.y, fmaf(q.z, q.z, q.w * q.w))));
    return make_float4(q.x * inv, q.y * inv, q.z * inv, q.w * inv);
}

// s(w) = 0.25 * acos(w)/sqrt(1-w^2), one trans op total.
// F(v) = 0.25*theta/sin(theta) at a=1-v:  exact series 0.25*(1 + v/3 + 2v^2/15
//   + 2v^3/35 + 8v^4/315 + 8v^5/693 + 16v^6/3003 + 112v^7/45045 + ...), deg-9.
__device__ __forceinline__ float log_scale(float w) {
    float wc = fminf(fmaxf(w, -1.0f + 1e-7f), 1.0f - 1e-7f);
    float a = fabsf(wc);
    float v = 1.0f - a;
    float F = fmaf(v, 1.3856e-4f, 2.9252e-4f);
    F = fmaf(v, F, 6.2160e-4f);
    F = fmaf(v, F, 1.3320e-3f);
    F = fmaf(v, F, 2.8860e-3f);
    F = fmaf(v, F, 6.34921e-3f);
    F = fmaf(v, F, 1.428571e-2f);
    F = fmaf(v, F, 3.333333e-2f);
    F = fmaf(v, F, 8.333333e-2f);
    F = fmaf(v, F, 0.25f);
    float R = frsq(fmaf(-wc, wc, 1.0f));        // clamp keeps 1-w^2 >= ~2e-7
    return (w >= 0.0f) ? F : fmaf(0.78539816f, R, -F);
}

__global__ __launch_bounds__(256) void karcher_kernel(
    const float4* __restrict__ aud, const float4* __restrict__ vis,
    const float4* __restrict__ txt, const float4* __restrict__ gen,
    float* __restrict__ out, float* __restrict__ ws)
{
    const int i = blockIdx.x * 256 + threadIdx.x;

    float4 p0 = qnorm_fast(aud[i]);
    float4 p1 = qnorm_fast(vis[i]);
    float4 p2 = qnorm_fast(txt[i]);
    float4 p3 = qnorm_fast(gen[i]);

    float4 mu = p0;

    #pragma unroll 1
    for (int it = 0; it < 10; ++it) {
        // w_k = Re(mu^-1 (x) p_k) = <mu, p_k>   (mu unit to ~1e-6)
        float w0 = fmaf(mu.x, p0.x, fmaf(mu.y, p0.y, fmaf(mu.z, p0.z, mu.w * p0.w)));
        float w1 = fmaf(mu.x, p1.x, fmaf(mu.y, p1.y, fmaf(mu.z, p1.z, mu.w * p1.w)));
        float w2 = fmaf(mu.x, p2.x, fmaf(mu.y, p2.y, fmaf(mu.z, p2.z, mu.w * p2.w)));
        float w3 = fmaf(mu.x, p3.x, fmaf(mu.y, p3.y, fmaf(mu.z, p3.z, mu.w * p3.w)));

        float s0 = log_scale(w0), s1 = log_scale(w1), s2 = log_scale(w2), s3 = log_scale(w3);

        // S = sum s_k * vec(p_k);  sigma = sum s_k * w-comp(p_k)
        float Sx = fmaf(s0, p0.y, fmaf(s1, p1.y, fmaf(s2, p2.y, s3 * p3.y)));
        float Sy = fmaf(s0, p0.z, fmaf(s1, p1.z, fmaf(s2, p2.z, s3 * p3.z)));
        float Sz = fmaf(s0, p0.w, fmaf(s1, p1.w, fmaf(s2, p2.w, s3 * p3.w)));
        float sg = fmaf(s0, p0.x, fmaf(s1, p1.x, fmaf(s2, p2.x, s3 * p3.x)));

        // mean_v = m0*S - sigma*m - m x S   (weights folded into s_k)
        float cx = fmaf(mu.z, Sz, -mu.w * Sy);
        float cy = fmaf(mu.w, Sx, -mu.y * Sz);
        float cz = fmaf(mu.y, Sy, -mu.z * Sx);
        float vx = fmaf(mu.x, Sx, -fmaf(sg, mu.y, cx));
        float vy = fmaf(mu.x, Sy, -fmaf(sg, mu.z, cy));
        float vz = fmaf(mu.x, Sz, -fmaf(sg, mu.w, cz));

        // delta_mu = exp(mean_v): cos(th) and sin(th)/th as polys in x = th^2
        // (x in [0, pi^2]; sinc deg-6 err<=7e-6, cos deg-7 err<=4.4e-6)
        float x = fmaf(vx, vx, fmaf(vy, vy, vz * vz));
        float sc = fmaf(x, 1.60590438e-10f, -2.50521084e-8f);
        sc = fmaf(x, sc, 2.75573192e-6f);
        sc = fmaf(x, sc, -1.98412698e-4f);
        sc = fmaf(x, sc, 8.33333333e-3f);
        sc = fmaf(x, sc, -1.66666667e-1f);
        sc = fmaf(x, sc, 1.0f);
        float dw = fmaf(x, -1.14707456e-11f, 2.08767570e-9f);
        dw = fmaf(x, dw, -2.75573192e-7f);
        dw = fmaf(x, dw, 2.48015873e-5f);
        dw = fmaf(x, dw, -1.38888889e-3f);
        dw = fmaf(x, dw, 4.16666667e-2f);
        dw = fmaf(x, dw, -0.5f);
        dw = fmaf(x, dw, 1.0f);
        float dx = sc * vx, dy = sc * vy, dz = sc * vz;

        // mu = mu (x) dm   (no renormalize; drift ~1ulp/iter)
        float4 nmu;
        nmu.x = fmaf(mu.x, dw, -fmaf(mu.y, dx, fmaf(mu.z, dy, mu.w * dz)));
        nmu.y = fmaf(mu.x, dx, fmaf(mu.y, dw, fmaf(mu.z, dz, -mu.w * dy)));
        nmu.z = fmaf(mu.x, dy, fmaf(-mu.y, dz, fmaf(mu.z, dw, mu.w * dx)));
        nmu.w = fmaf(mu.x, dz, fmaf(mu.y, dy, fmaf(-mu.z, dx, mu.w * dw)));
        mu = nmu;
    }

    mu = qnorm_fast(mu);   // reference's final barycenter is normalized

    // Output 0: barycenter (B, L, 4)
    reinterpret_cast<float4*>(out)[i] = mu;

    // Output 1: eta = angle(det_s)/pi. det_s imag parts are (a*b - a*b) == 0
    // exactly in fp32; real part = |q|^2 > 0  =>  angle == 0 exactly.
    out[4 * NPTS + i] = 0.0f;

    // Output 2 contribution: |mu - mu/(|mu|+1e-12)|^2  (precise ops, runs once)
    float n = sqrtf(mu.x * mu.x + mu.y * mu.y + mu.z * mu.z + mu.w * mu.w) + 1e-12f;
    float invn = 1.0f / n;
    float ex = mu.x - mu.x * invn;
    float ey = mu.y - mu.y * invn;
    float ez = mu.z - mu.z * invn;
    float ew = mu.w - mu.w * invn;
    float ss = ex * ex + ey * ey + ez * ez + ew * ew;

    // wave(64) shfl reduce -> LDS across the 4 waves -> one plain store/block
    #pragma unroll
    for (int off = 32; off > 0; off >>= 1)
        ss += __shfl_down(ss, off, 64);
    __shared__ float part[4];
    if ((threadIdx.x & 63) == 0) part[threadIdx.x >> 6] = ss;
    __syncthreads();
    if (threadIdx.x == 0)
        ws[blockIdx.x] = part[0] + part[1] + part[2] + part[3];
}

__global__ __launch_bounds__(256) void finish_kernel(
    const float* __restrict__ ws, float* __restrict__ out)
{
    float s = 0.0f;
    #pragma unroll 4
    for (int k = threadIdx.x; k < NBLK; k += 256)
        s += ws[k];
    #pragma unroll
    for (int off = 32; off > 0; off >>= 1)
        s += __shfl_down(s, off, 64);
    __shared__ float part[4];
    if ((threadIdx.x & 63) == 0) part[threadIdx.x >> 6] = s;
    __syncthreads();
    if (threadIdx.x == 0)
        out[5 * NPTS] = 1.0f / (1.0f + sqrtf(part[0] + part[1] + part[2] + part[3]));
}

extern "C" void kernel_launch(void* const* d_in, const int* in_sizes, int n_in,
                              void* d_out, int out_size, void* d_ws, size_t ws_size,
                              hipStream_t stream) {
    const float4* aud = (const float4*)d_in[0];
    const float4* vis = (const float4*)d_in[1];
    const float4* txt = (const float4*)d_in[2];
    const float4* gen = (const float4*)d_in[3];
    float* out = (float*)d_out;
    float* ws = (float*)d_ws;   // NBLK floats, fully overwritten every call

    karcher_kernel<<<NBLK, 256, 0, stream>>>(aud, vis, txt, gen, out, ws);
    finish_kernel<<<1, 256, 0, stream>>>(ws, out);
}

// Round 6
// 145.192 us; speedup vs baseline: 1.3035x; 1.3035x over previous
//
#include <hip/hip_runtime.h>

// SynesthesiaCentralOrchestrator: per-point Karcher mean of 4 unit quaternions,
// 10 fixed iterations (global convergence flag provably never fires in fp32).
// Quaternion stored as float4: .x=w, .y=x, .z=y, .w=z.
//
// R3: per-block partials instead of single-address atomicAdd (was ~800us drain).
// R4: log-map needs only w_k = <mu,p_k>; A&S acos poly + 2 rsq (best measured).
// R5 (reverted): poly-for-trans swap regressed; calibrated issue model:
//     VALU = 2 cy, trans = 4 cy (quarter-rate). Minimize 2V+4T.
// R6: linear-combination update. T = sum s_k p_k, d = <mu,T>, E = T - d*mu:
//     mean_v = vec(mu^-1 x T)  (log-sum is linear in p_k)
//     theta^2 = |E|^2          (mu unit; E = mu x (0, mean_v))
//     mu_new  = cos(theta)*mu + sinc(theta)*E   (exp map, polys in theta^2)
//     Deletes the cross/combine (12 ops) and final Hamilton product (16 FMA).
//     E via fused fma is cancellation-free even for near-antipodal |T|~1e3.
//     Also: fast-math epilogue, full unroll.

#define NPTS (2048 * 2048)
#define NBLK (NPTS / 256)   // 16384 blocks; ws usage = 64 KB

__device__ __forceinline__ float frcp(float x) { return __builtin_amdgcn_rcpf(x); }
__device__ __forceinline__ float frsq(float x) { return __builtin_amdgcn_rsqf(x); }
__device__ __forceinline__ float fsqrt(float x) { return __builtin_amdgcn_sqrtf(x); }

__device__ __forceinline__ float4 qnorm_fast(const float4 q) {
    float inv = frsq(fmaf(q.x, q.x, fmaf(q.y, q.y, fmaf(q.z, q.z, q.w * q.w))));
    return make_float4(q.x * inv, q.y * inv, q.z * inv, q.w * inv);
}

// s(w) = 0.25 * acos(w)/sqrt(1-w^2)  via  acos(a) ~= sqrt(1-a)*t(a), a=|w|
// (A&S 4.4.45, |err| <= 6.8e-5 rad). Coefficients pre-scaled by 0.25.
__device__ __forceinline__ float log_scale(float w) {
    float a = fminf(fabsf(w), 0.9999999f);      // guard 1-a >= 1e-7 (|w| can be 1+3e-6)
    float t = fmaf(a, fmaf(a, fmaf(a, -0.004682325f, 0.018565250f), -0.053028600f),
                   0.392682200f);               // 0.25 * t(a)
    float r1 = frsq(1.0f + a);
    float r2 = frsq(1.0f - a);
    float u = fmaf(0.785398163f, r2, -t);       // (pi/4)*r2 - t
    return r1 * ((w >= 0.0f) ? t : u);
}

// cos(sqrt(x)) and sin(sqrt(x))/sqrt(x) for x = theta^2 in [0, pi^2].
// sinc deg-6 err<=7e-6, cos deg-7 err<=4.4e-6.
__device__ __forceinline__ float sinc_poly(float x) {
    float s = fmaf(x, 1.60590438e-10f, -2.50521084e-8f);
    s = fmaf(x, s, 2.75573192e-6f);
    s = fmaf(x, s, -1.98412698e-4f);
    s = fmaf(x, s, 8.33333333e-3f);
    s = fmaf(x, s, -1.66666667e-1f);
    return fmaf(x, s, 1.0f);
}
__device__ __forceinline__ float cos_poly(float x) {
    float c = fmaf(x, -1.14707456e-11f, 2.08767570e-9f);
    c = fmaf(x, c, -2.75573192e-7f);
    c = fmaf(x, c, 2.48015873e-5f);
    c = fmaf(x, c, -1.38888889e-3f);
    c = fmaf(x, c, 4.16666667e-2f);
    c = fmaf(x, c, -0.5f);
    return fmaf(x, c, 1.0f);
}

__global__ __launch_bounds__(256) void karcher_kernel(
    const float4* __restrict__ aud, const float4* __restrict__ vis,
    const float4* __restrict__ txt, const float4* __restrict__ gen,
    float* __restrict__ out, float* __restrict__ ws)
{
    const int i = blockIdx.x * 256 + threadIdx.x;

    float4 p0 = qnorm_fast(aud[i]);
    float4 p1 = qnorm_fast(vis[i]);
    float4 p2 = qnorm_fast(txt[i]);
    float4 p3 = qnorm_fast(gen[i]);

    float4 mu = p0;

    #pragma unroll
    for (int it = 0; it < 10; ++it) {
        // w_k = Re(mu^-1 (x) p_k) = <mu, p_k>
        float w0 = fmaf(mu.x, p0.x, fmaf(mu.y, p0.y, fmaf(mu.z, p0.z, mu.w * p0.w)));
        float w1 = fmaf(mu.x, p1.x, fmaf(mu.y, p1.y, fmaf(mu.z, p1.z, mu.w * p1.w)));
        float w2 = fmaf(mu.x, p2.x, fmaf(mu.y, p2.y, fmaf(mu.z, p2.z, mu.w * p2.w)));
        float w3 = fmaf(mu.x, p3.x, fmaf(mu.y, p3.y, fmaf(mu.z, p3.z, mu.w * p3.w)));

        float s0 = log_scale(w0), s1 = log_scale(w1), s2 = log_scale(w2), s3 = log_scale(w3);

        // T = sum s_k * p_k   (quaternion; weights 1/4 folded into s_k)
        float Tw = fmaf(s0, p0.x, fmaf(s1, p1.x, fmaf(s2, p2.x, s3 * p3.x)));
        float Tx = fmaf(s0, p0.y, fmaf(s1, p1.y, fmaf(s2, p2.y, s3 * p3.y)));
        float Ty = fmaf(s0, p0.z, fmaf(s1, p1.z, fmaf(s2, p2.z, s3 * p3.z)));
        float Tz = fmaf(s0, p0.w, fmaf(s1, p1.w, fmaf(s2, p2.w, s3 * p3.w)));

        // d = <mu,T>;  E = T - d*mu = mu (x) (0, mean_v);  theta^2 = |E|^2
        float d  = fmaf(mu.x, Tw, fmaf(mu.y, Tx, fmaf(mu.z, Ty, mu.w * Tz)));
        float Ew = fmaf(-d, mu.x, Tw);
        float Ex = fmaf(-d, mu.y, Tx);
        float Ey = fmaf(-d, mu.z, Ty);
        float Ez = fmaf(-d, mu.w, Tz);
        float x  = fmaf(Ew, Ew, fmaf(Ex, Ex, fmaf(Ey, Ey, Ez * Ez)));

        // mu = mu (x) exp(mean_v) = cos(th)*mu + sinc(th)*E
        float sc = sinc_poly(x);
        float c  = cos_poly(x);
        mu.x = fmaf(c, mu.x, sc * Ew);
        mu.y = fmaf(c, mu.y, sc * Ex);
        mu.z = fmaf(c, mu.z, sc * Ey);
        mu.w = fmaf(c, mu.w, sc * Ez);
    }

    mu = qnorm_fast(mu);   // reference's final barycenter is normalized

    // Output 0: barycenter (B, L, 4)
    reinterpret_cast<float4*>(out)[i] = mu;

    // Output 1: eta = angle(det_s)/pi. det_s imag parts are (a*b - a*b) == 0
    // exactly in fp32; real part = |q|^2 > 0  =>  angle == 0 exactly.
    out[4 * NPTS + i] = 0.0f;

    // Output 2 contribution: |mu - mu/(|mu|+1e-12)|^2  (fast ops; value ~1e-14,
    // veracity ~= 1 - O(1e-4) for both us and reference; threshold 2e-2)
    float nn = fmaf(mu.x, mu.x, fmaf(mu.y, mu.y, fmaf(mu.z, mu.z, mu.w * mu.w)));
    float invn = frcp(fsqrt(nn) + 1e-12f);
    float ex = fmaf(-mu.x, invn, mu.x);
    float ey = fmaf(-mu.y, invn, mu.y);
    float ez = fmaf(-mu.z, invn, mu.z);
    float ew = fmaf(-mu.w, invn, mu.w);
    float ss = fmaf(ex, ex, fmaf(ey, ey, fmaf(ez, ez, ew * ew)));

    // wave(64) shfl reduce -> LDS across the 4 waves -> one plain store/block
    #pragma unroll
    for (int off = 32; off > 0; off >>= 1)
        ss += __shfl_down(ss, off, 64);
    __shared__ float part[4];
    if ((threadIdx.x & 63) == 0) part[threadIdx.x >> 6] = ss;
    __syncthreads();
    if (threadIdx.x == 0)
        ws[blockIdx.x] = part[0] + part[1] + part[2] + part[3];
}

__global__ __launch_bounds__(256) void finish_kernel(
    const float* __restrict__ ws, float* __restrict__ out)
{
    float s = 0.0f;
    #pragma unroll 4
    for (int k = threadIdx.x; k < NBLK; k += 256)
        s += ws[k];
    #pragma unroll
    for (int off = 32; off > 0; off >>= 1)
        s += __shfl_down(s, off, 64);
    __shared__ float part[4];
    if ((threadIdx.x & 63) == 0) part[threadIdx.x >> 6] = s;
    __syncthreads();
    if (threadIdx.x == 0)
        out[5 * NPTS] = 1.0f / (1.0f + sqrtf(part[0] + part[1] + part[2] + part[3]));
}

extern "C" void kernel_launch(void* const* d_in, const int* in_sizes, int n_in,
                              void* d_out, int out_size, void* d_ws, size_t ws_size,
                              hipStream_t stream) {
    const float4* aud = (const float4*)d_in[0];
    const float4* vis = (const float4*)d_in[1];
    const float4* txt = (const float4*)d_in[2];
    const float4* gen = (const float4*)d_in[3];
    float* out = (float*)d_out;
    float* ws = (float*)d_ws;   // NBLK floats, fully overwritten every call

    karcher_kernel<<<NBLK, 256, 0, stream>>>(aud, vis, txt, gen, out, ws);
    finish_kernel<<<1, 256, 0, stream>>>(ws, out);
}

// Round 7
// 145.071 us; speedup vs baseline: 1.3046x; 1.0008x over previous
//
#include <hip/hip_runtime.h>

// SynesthesiaCentralOrchestrator: per-point Karcher mean of 4 unit quaternions,
// 10 fixed iterations (global convergence flag provably never fires in fp32).
// Quaternion stored as float4: .x=w, .y=x, .z=y, .w=z.
//
// R3: per-block partials instead of single-address atomicAdd (was ~800us drain).
// R6: linear-combination update: T = sum s_k p_k, d = <mu,T>, E = T - d*mu,
//     theta^2 = |E|^2, mu' = cos(th)*mu + sinc(th)*E.
// R7: (a) rolled loop (#pragma unroll 1): gfx950 has no v_fmaak/v_fmamk and
//         VOP3 fma forbids literals -> unrolled body re-materializes ~21 poly
//         constants per iter; rolled loop lets the compiler hoist them once.
//     (b) single-trans log_scale: acos(w) = pi - acos(|w|), so
//         s = (w>=0) ? P(|w|) : (pi/4)*rsqrt(1-w^2) - P(|w|),
//         P = 0.25*theta/sin(theta) = deg-7 series in v = 1-|w| (err<=5.6e-4).
//         Trans ops 8 -> 4 per iteration.
//     (c) peeled iteration 1: mu = p0 exactly -> w0=1, s0=0.25, and p0's
//         tangent contribution cancels exactly in E; skip its dot + log.

#define NPTS (2048 * 2048)
#define NBLK (NPTS / 256)   // 16384 blocks; ws usage = 64 KB

__device__ __forceinline__ float frcp(float x) { return __builtin_amdgcn_rcpf(x); }
__device__ __forceinline__ float frsq(float x) { return __builtin_amdgcn_rsqf(x); }
__device__ __forceinline__ float fsqrt(float x) { return __builtin_amdgcn_sqrtf(x); }

__device__ __forceinline__ float4 qnorm_fast(const float4 q) {
    float inv = frsq(fmaf(q.x, q.x, fmaf(q.y, q.y, fmaf(q.z, q.z, q.w * q.w))));
    return make_float4(q.x * inv, q.y * inv, q.z * inv, q.w * inv);
}

// s(w) = 0.25*acos(w)/sqrt(1-w^2), ONE trans op.
// P(v) = 0.25*theta/sin(theta) at |w| = 1-v: exact series
//   0.25*(1 + v/3 + 2v^2/15 + 2v^3/35 + 8v^4/315 + 8v^5/693 + 16v^6/3003
//         + 112v^7/45045), err <= 5.6e-4 at v=1.
// Negative w: s = (pi/4)*R - P,  R = rsqrt(max(1-w^2, 2e-7)) (matches the
// reference's clip(w, -1+1e-7, ...) tail behavior).
__device__ __forceinline__ float log_scale(float w) {
    float v = 1.0f - fabsf(w);
    float F = fmaf(v, 6.216216e-4f, 1.332001e-3f);
    F = fmaf(v, F, 2.886003e-3f);
    F = fmaf(v, F, 6.349206e-3f);
    F = fmaf(v, F, 1.4285714e-2f);
    F = fmaf(v, F, 3.3333333e-2f);
    F = fmaf(v, F, 8.3333333e-2f);
    F = fmaf(v, F, 0.25f);
    float u = fmaxf(fmaf(-w, w, 1.0f), 2e-7f);
    float R = frsq(u);
    return (w >= 0.0f) ? F : fmaf(0.78539816f, R, -F);
}

// cos(sqrt(x)) and sin(sqrt(x))/sqrt(x) for x = theta^2 in [0, pi^2].
__device__ __forceinline__ float sinc_poly(float x) {
    float s = fmaf(x, 1.60590438e-10f, -2.50521084e-8f);
    s = fmaf(x, s, 2.75573192e-6f);
    s = fmaf(x, s, -1.98412698e-4f);
    s = fmaf(x, s, 8.33333333e-3f);
    s = fmaf(x, s, -1.66666667e-1f);
    return fmaf(x, s, 1.0f);
}
__device__ __forceinline__ float cos_poly(float x) {
    float c = fmaf(x, -1.14707456e-11f, 2.08767570e-9f);
    c = fmaf(x, c, -2.75573192e-7f);
    c = fmaf(x, c, 2.48015873e-5f);
    c = fmaf(x, c, -1.38888889e-3f);
    c = fmaf(x, c, 4.16666667e-2f);
    c = fmaf(x, c, -0.5f);
    return fmaf(x, c, 1.0f);
}

__global__ __launch_bounds__(256) void karcher_kernel(
    const float4* __restrict__ aud, const float4* __restrict__ vis,
    const float4* __restrict__ txt, const float4* __restrict__ gen,
    float* __restrict__ out, float* __restrict__ ws)
{
    const int i = blockIdx.x * 256 + threadIdx.x;

    float4 p0 = qnorm_fast(aud[i]);
    float4 p1 = qnorm_fast(vis[i]);
    float4 p2 = qnorm_fast(txt[i]);
    float4 p3 = qnorm_fast(gen[i]);

    float4 mu;

    // ---- Peeled iteration 1: mu = p0, w0 = 1 (to 1 ulp), s0 = 0.25; p0's
    // tangent contribution cancels exactly in E = T - d*mu. ----
    {
        float w1 = fmaf(p0.x, p1.x, fmaf(p0.y, p1.y, fmaf(p0.z, p1.z, p0.w * p1.w)));
        float w2 = fmaf(p0.x, p2.x, fmaf(p0.y, p2.y, fmaf(p0.z, p2.z, p0.w * p2.w)));
        float w3 = fmaf(p0.x, p3.x, fmaf(p0.y, p3.y, fmaf(p0.z, p3.z, p0.w * p3.w)));
        float s1 = log_scale(w1), s2 = log_scale(w2), s3 = log_scale(w3);

        float Tw = fmaf(s1, p1.x, fmaf(s2, p2.x, fmaf(s3, p3.x, 0.25f * p0.x)));
        float Tx = fmaf(s1, p1.y, fmaf(s2, p2.y, fmaf(s3, p3.y, 0.25f * p0.y)));
        float Ty = fmaf(s1, p1.z, fmaf(s2, p2.z, fmaf(s3, p3.z, 0.25f * p0.z)));
        float Tz = fmaf(s1, p1.w, fmaf(s2, p2.w, fmaf(s3, p3.w, 0.25f * p0.w)));

        float d  = fmaf(p0.x, Tw, fmaf(p0.y, Tx, fmaf(p0.z, Ty, p0.w * Tz)));
        float Ew = fmaf(-d, p0.x, Tw);
        float Ex = fmaf(-d, p0.y, Tx);
        float Ey = fmaf(-d, p0.z, Ty);
        float Ez = fmaf(-d, p0.w, Tz);
        float x  = fmaf(Ew, Ew, fmaf(Ex, Ex, fmaf(Ey, Ey, Ez * Ez)));

        float sc = sinc_poly(x);
        float c  = cos_poly(x);
        mu.x = fmaf(c, p0.x, sc * Ew);
        mu.y = fmaf(c, p0.y, sc * Ex);
        mu.z = fmaf(c, p0.z, sc * Ey);
        mu.w = fmaf(c, p0.w, sc * Ez);
    }

    // ---- Iterations 2..10 (rolled: constants hoisted once) ----
    #pragma unroll 1
    for (int it = 0; it < 9; ++it) {
        float w0 = fmaf(mu.x, p0.x, fmaf(mu.y, p0.y, fmaf(mu.z, p0.z, mu.w * p0.w)));
        float w1 = fmaf(mu.x, p1.x, fmaf(mu.y, p1.y, fmaf(mu.z, p1.z, mu.w * p1.w)));
        float w2 = fmaf(mu.x, p2.x, fmaf(mu.y, p2.y, fmaf(mu.z, p2.z, mu.w * p2.w)));
        float w3 = fmaf(mu.x, p3.x, fmaf(mu.y, p3.y, fmaf(mu.z, p3.z, mu.w * p3.w)));

        float s0 = log_scale(w0), s1 = log_scale(w1), s2 = log_scale(w2), s3 = log_scale(w3);

        float Tw = fmaf(s0, p0.x, fmaf(s1, p1.x, fmaf(s2, p2.x, s3 * p3.x)));
        float Tx = fmaf(s0, p0.y, fmaf(s1, p1.y, fmaf(s2, p2.y, s3 * p3.y)));
        float Ty = fmaf(s0, p0.z, fmaf(s1, p1.z, fmaf(s2, p2.z, s3 * p3.z)));
        float Tz = fmaf(s0, p0.w, fmaf(s1, p1.w, fmaf(s2, p2.w, s3 * p3.w)));

        float d  = fmaf(mu.x, Tw, fmaf(mu.y, Tx, fmaf(mu.z, Ty, mu.w * Tz)));
        float Ew = fmaf(-d, mu.x, Tw);
        float Ex = fmaf(-d, mu.y, Tx);
        float Ey = fmaf(-d, mu.z, Ty);
        float Ez = fmaf(-d, mu.w, Tz);
        float x  = fmaf(Ew, Ew, fmaf(Ex, Ex, fmaf(Ey, Ey, Ez * Ez)));

        float sc = sinc_poly(x);
        float c  = cos_poly(x);
        mu.x = fmaf(c, mu.x, sc * Ew);
        mu.y = fmaf(c, mu.y, sc * Ex);
        mu.z = fmaf(c, mu.z, sc * Ey);
        mu.w = fmaf(c, mu.w, sc * Ez);
    }

    mu = qnorm_fast(mu);   // reference's final barycenter is normalized

    // Output 0: barycenter (B, L, 4)
    reinterpret_cast<float4*>(out)[i] = mu;

    // Output 1: eta = angle(det_s)/pi. det_s imag parts are (a*b - a*b) == 0
    // exactly in fp32; real part = |q|^2 > 0  =>  angle == 0 exactly.
    out[4 * NPTS + i] = 0.0f;

    // Output 2 contribution: |mu - mu/(|mu|+1e-12)|^2
    float nn = fmaf(mu.x, mu.x, fmaf(mu.y, mu.y, fmaf(mu.z, mu.z, mu.w * mu.w)));
    float invn = frcp(fsqrt(nn) + 1e-12f);
    float ex = fmaf(-mu.x, invn, mu.x);
    float ey = fmaf(-mu.y, invn, mu.y);
    float ez = fmaf(-mu.z, invn, mu.z);
    float ew = fmaf(-mu.w, invn, mu.w);
    float ss = fmaf(ex, ex, fmaf(ey, ey, fmaf(ez, ez, ew * ew)));

    // wave(64) shfl reduce -> LDS across the 4 waves -> one plain store/block
    #pragma unroll
    for (int off = 32; off > 0; off >>= 1)
        ss += __shfl_down(ss, off, 64);
    __shared__ float part[4];
    if ((threadIdx.x & 63) == 0) part[threadIdx.x >> 6] = ss;
    __syncthreads();
    if (threadIdx.x == 0)
        ws[blockIdx.x] = part[0] + part[1] + part[2] + part[3];
}

__global__ __launch_bounds__(256) void finish_kernel(
    const float* __restrict__ ws, float* __restrict__ out)
{
    float s = 0.0f;
    #pragma unroll 4
    for (int k = threadIdx.x; k < NBLK; k += 256)
        s += ws[k];
    #pragma unroll
    for (int off = 32; off > 0; off >>= 1)
        s += __shfl_down(s, off, 64);
    __shared__ float part[4];
    if ((threadIdx.x & 63) == 0) part[threadIdx.x >> 6] = s;
    __syncthreads();
    if (threadIdx.x == 0)
        out[5 * NPTS] = 1.0f / (1.0f + sqrtf(part[0] + part[1] + part[2] + part[3]));
}

extern "C" void kernel_launch(void* const* d_in, const int* in_sizes, int n_in,
                              void* d_out, int out_size, void* d_ws, size_t ws_size,
                              hipStream_t stream) {
    const float4* aud = (const float4*)d_in[0];
    const float4* vis = (const float4*)d_in[1];
    const float4* txt = (const float4*)d_in[2];
    const float4* gen = (const float4*)d_in[3];
    float* out = (float*)d_out;
    float* ws = (float*)d_ws;   // NBLK floats, fully overwritten every call

    karcher_kernel<<<NBLK, 256, 0, stream>>>(aud, vis, txt, gen, out, ws);
    finish_kernel<<<1, 256, 0, stream>>>(ws, out);
}

// Round 8
// 135.101 us; speedup vs baseline: 1.4009x; 1.0738x over previous
//
#include <hip/hip_runtime.h>

// SynesthesiaCentralOrchestrator: per-point Karcher mean of 4 unit quaternions,
// 10 fixed iterations (global convergence flag provably never fires in fp32).
// Quaternion stored as float4: .x=w, .y=x, .z=y, .w=z.
//
// R3: per-block partials instead of single-address atomicAdd (was ~800us drain).
// R6: linear-combination update: T = sum s_k p_k, d = <mu,T> = sum s_k w_k,
//     E = T - d*mu, theta^2 = |E|^2, mu' = cos(th)*mu + sinc(th)*E.
// R7: rolled loop (saves ~14 inst/iter of literal re-materialization) + peel.
// R8: (a) revert log_scale to the accurate 2-rsq A&S form (absmax 0.0039
//         headroom vs 0.0137 with the deg-7 series; measured fast in R6);
//     (b) TWO points per thread: independent chains double per-thread ILP.
//         Discriminates latency-bubbles vs issue-bound for the unexplained
//         1.8x gap between static issue count (~2900 cy/wave) and measured
//         (~5200 cy/wave). Latency-bound -> ~110us; issue-bound -> neutral.

#define NPTS (2048 * 2048)
#define NBLK (NPTS / 512)   // 8192 blocks; ws usage = 32 KB

__device__ __forceinline__ float frcp(float x) { return __builtin_amdgcn_rcpf(x); }
__device__ __forceinline__ float frsq(float x) { return __builtin_amdgcn_rsqf(x); }
__device__ __forceinline__ float fsqrt(float x) { return __builtin_amdgcn_sqrtf(x); }

__device__ __forceinline__ float4 qnorm_fast(const float4 q) {
    float inv = frsq(fmaf(q.x, q.x, fmaf(q.y, q.y, fmaf(q.z, q.z, q.w * q.w))));
    return make_float4(q.x * inv, q.y * inv, q.z * inv, q.w * inv);
}

// s(w) = 0.25 * acos(w)/sqrt(1-w^2)  via  acos(a) ~= sqrt(1-a)*t(a), a=|w|
// (A&S 4.4.45, |err| <= 6.8e-5 rad). Coefficients pre-scaled by 0.25.
__device__ __forceinline__ float log_scale(float w) {
    float a = fminf(fabsf(w), 0.9999999f);      // guard 1-a >= 1e-7
    float t = fmaf(a, fmaf(a, fmaf(a, -0.004682325f, 0.018565250f), -0.053028600f),
                   0.392682200f);               // 0.25 * t(a)
    float r1 = frsq(1.0f + a);
    float r2 = frsq(1.0f - a);
    float u = fmaf(0.785398163f, r2, -t);       // (pi/4)*r2 - t
    return r1 * ((w >= 0.0f) ? t : u);
}

// cos(sqrt(x)) and sin(sqrt(x))/sqrt(x) for x = theta^2 in [0, pi^2].
__device__ __forceinline__ float sinc_poly(float x) {
    float s = fmaf(x, 1.60590438e-10f, -2.50521084e-8f);
    s = fmaf(x, s, 2.75573192e-6f);
    s = fmaf(x, s, -1.98412698e-4f);
    s = fmaf(x, s, 8.33333333e-3f);
    s = fmaf(x, s, -1.66666667e-1f);
    return fmaf(x, s, 1.0f);
}
__device__ __forceinline__ float cos_poly(float x) {
    float c = fmaf(x, -1.14707456e-11f, 2.08767570e-9f);
    c = fmaf(x, c, -2.75573192e-7f);
    c = fmaf(x, c, 2.48015873e-5f);
    c = fmaf(x, c, -1.38888889e-3f);
    c = fmaf(x, c, 4.16666667e-2f);
    c = fmaf(x, c, -0.5f);
    return fmaf(x, c, 1.0f);
}

// One Karcher update given precomputed s0 (peel passes 0.25, main passes log0).
__device__ __forceinline__ float4 karcher_update(
    float4 mu, float s0, float w0,
    const float4 p0, const float4 p1, const float4 p2, const float4 p3)
{
    float w1 = fmaf(mu.x, p1.x, fmaf(mu.y, p1.y, fmaf(mu.z, p1.z, mu.w * p1.w)));
    float w2 = fmaf(mu.x, p2.x, fmaf(mu.y, p2.y, fmaf(mu.z, p2.z, mu.w * p2.w)));
    float w3 = fmaf(mu.x, p3.x, fmaf(mu.y, p3.y, fmaf(mu.z, p3.z, mu.w * p3.w)));
    float s1 = log_scale(w1), s2 = log_scale(w2), s3 = log_scale(w3);

    // T = sum s_k p_k  (weights 1/4 folded into s_k)
    float Tw = fmaf(s0, p0.x, fmaf(s1, p1.x, fmaf(s2, p2.x, s3 * p3.x)));
    float Tx = fmaf(s0, p0.y, fmaf(s1, p1.y, fmaf(s2, p2.y, s3 * p3.y)));
    float Ty = fmaf(s0, p0.z, fmaf(s1, p1.z, fmaf(s2, p2.z, s3 * p3.z)));
    float Tz = fmaf(s0, p0.w, fmaf(s1, p1.w, fmaf(s2, p2.w, s3 * p3.w)));

    // d = <mu,T> = sum s_k w_k  (reuse dots: 4 fma, no extra vector dot)
    float d = fmaf(s0, w0, fmaf(s1, w1, fmaf(s2, w2, s3 * w3)));

    float Ew = fmaf(-d, mu.x, Tw);
    float Ex = fmaf(-d, mu.y, Tx);
    float Ey = fmaf(-d, mu.z, Ty);
    float Ez = fmaf(-d, mu.w, Tz);
    float x  = fmaf(Ew, Ew, fmaf(Ex, Ex, fmaf(Ey, Ey, Ez * Ez)));

    float sc = sinc_poly(x);
    float c  = cos_poly(x);
    float4 r;
    r.x = fmaf(c, mu.x, sc * Ew);
    r.y = fmaf(c, mu.y, sc * Ex);
    r.z = fmaf(c, mu.z, sc * Ey);
    r.w = fmaf(c, mu.w, sc * Ez);
    return r;
}

__global__ __launch_bounds__(256) void karcher_kernel(
    const float4* __restrict__ aud, const float4* __restrict__ vis,
    const float4* __restrict__ txt, const float4* __restrict__ gen,
    float* __restrict__ out, float* __restrict__ ws)
{
    const int i0 = (blockIdx.x * 256 + threadIdx.x) * 2;   // two points per thread

    float4 p[2][4], mu[2];
    #pragma unroll
    for (int j = 0; j < 2; ++j) {
        p[j][0] = qnorm_fast(aud[i0 + j]);
        p[j][1] = qnorm_fast(vis[i0 + j]);
        p[j][2] = qnorm_fast(txt[i0 + j]);
        p[j][3] = qnorm_fast(gen[i0 + j]);
    }

    // Peeled iteration 1: mu = p0 -> w0 = 1 (to 1 ulp), s0 = 0.25.
    #pragma unroll
    for (int j = 0; j < 2; ++j)
        mu[j] = karcher_update(p[j][0], 0.25f, 1.0f,
                               p[j][0], p[j][1], p[j][2], p[j][3]);

    // Iterations 2..10 (rolled: constants hoisted; 2 independent chains for ILP)
    #pragma unroll 1
    for (int it = 0; it < 9; ++it) {
        #pragma unroll
        for (int j = 0; j < 2; ++j) {
            float4 m = mu[j];
            const float4 q0 = p[j][0];
            float w0 = fmaf(m.x, q0.x, fmaf(m.y, q0.y, fmaf(m.z, q0.z, m.w * q0.w)));
            float s0 = log_scale(w0);
            mu[j] = karcher_update(m, s0, w0, q0, p[j][1], p[j][2], p[j][3]);
        }
    }

    float ss = 0.0f;
    #pragma unroll
    for (int j = 0; j < 2; ++j) {
        float4 m = qnorm_fast(mu[j]);   // reference's final normalize

        // Output 0: barycenter (B, L, 4)
        reinterpret_cast<float4*>(out)[i0 + j] = m;

        // Output 1: eta = angle(det_s)/pi. det_s imag parts are (a*b - a*b)==0
        // exactly in fp32; real part = |q|^2 > 0  =>  angle == 0 exactly.
        out[4 * NPTS + i0 + j] = 0.0f;

        // Output 2 contribution: |m - m/(|m|+1e-12)|^2
        float nn = fmaf(m.x, m.x, fmaf(m.y, m.y, fmaf(m.z, m.z, m.w * m.w)));
        float invn = frcp(fsqrt(nn) + 1e-12f);
        float ex = fmaf(-m.x, invn, m.x);
        float ey = fmaf(-m.y, invn, m.y);
        float ez = fmaf(-m.z, invn, m.z);
        float ew = fmaf(-m.w, invn, m.w);
        ss += fmaf(ex, ex, fmaf(ey, ey, fmaf(ez, ez, ew * ew)));
    }

    // wave(64) shfl reduce -> LDS across the 4 waves -> one plain store/block
    #pragma unroll
    for (int off = 32; off > 0; off >>= 1)
        ss += __shfl_down(ss, off, 64);
    __shared__ float part[4];
    if ((threadIdx.x & 63) == 0) part[threadIdx.x >> 6] = ss;
    __syncthreads();
    if (threadIdx.x == 0)
        ws[blockIdx.x] = part[0] + part[1] + part[2] + part[3];
}

__global__ __launch_bounds__(256) void finish_kernel(
    const float* __restrict__ ws, float* __restrict__ out)
{
    float s = 0.0f;
    #pragma unroll 4
    for (int k = threadIdx.x; k < NBLK; k += 256)
        s += ws[k];
    #pragma unroll
    for (int off = 32; off > 0; off >>= 1)
        s += __shfl_down(s, off, 64);
    __shared__ float part[4];
    if ((threadIdx.x & 63) == 0) part[threadIdx.x >> 6] = s;
    __syncthreads();
    if (threadIdx.x == 0)
        out[5 * NPTS] = 1.0f / (1.0f + sqrtf(part[0] + part[1] + part[2] + part[3]));
}

extern "C" void kernel_launch(void* const* d_in, const int* in_sizes, int n_in,
                              void* d_out, int out_size, void* d_ws, size_t ws_size,
                              hipStream_t stream) {
    const float4* aud = (const float4*)d_in[0];
    const float4* vis = (const float4*)d_in[1];
    const float4* txt = (const float4*)d_in[2];
    const float4* gen = (const float4*)d_in[3];
    float* out = (float*)d_out;
    float* ws = (float*)d_ws;   // NBLK floats, fully overwritten every call

    karcher_kernel<<<NBLK, 256, 0, stream>>>(aud, vis, txt, gen, out, ws);
    finish_kernel<<<1, 256, 0, stream>>>(ws, out);
}

// Round 10
// 125.638 us; speedup vs baseline: 1.5064x; 1.0753x over previous
//
#include <hip/hip_runtime.h>

// SynesthesiaCentralOrchestrator: per-point Karcher mean of 4 unit quaternions,
// 10 fixed iterations. Quaternion float4: .x=w, .y=x, .z=y, .w=z.
//
// R3: per-block partials instead of single-address atomicAdd.
// R6: ambient linear-combination update: E = T - d*mu, mu' = c*mu + sc*E.
// R8: 2 independent chains/thread (ILP). 135us, absmax 0.0039. ISSUE-BOUND.
// R9 (reverted): Gram-basis iteration -> catastrophic cancellation in E.GE
//     (near-antipodal s ~ 1e3 coords, tiny ambient image). Back to ambient.
// R10: packed fp32. MI355X's 157.3 TF fp32 = v_pk_fma_f32 (VOP3P, 2 fp32/lane).
//     Pack each chain's TWO points into float2 ext-vectors (SoA per quat
//     component); all FMAs via __builtin_elementwise_fma -> llvm.fma.v2f32 ->
//     v_pk_fma_f32. Two packed chains per thread (4 points) keep R8's ILP.
//     Per-point op sequence identical to R8 -> identical numerics.

typedef float v2f __attribute__((ext_vector_type(2)));
typedef int   v2i __attribute__((ext_vector_type(2)));

#define NPTS (2048 * 2048)
#define NBLK (NPTS / 1024)   // 4096 blocks; ws usage = 16 KB

__device__ __forceinline__ float frcp(float x) { return __builtin_amdgcn_rcpf(x); }
__device__ __forceinline__ float frsq(float x) { return __builtin_amdgcn_rsqf(x); }
__device__ __forceinline__ float fsqrt(float x) { return __builtin_amdgcn_sqrtf(x); }

__device__ __forceinline__ v2f vfma(v2f a, v2f b, v2f c) {
    return __builtin_elementwise_fma(a, b, c);
}
__device__ __forceinline__ v2f vsplat(float s) { v2f r; r.x = s; r.y = s; return r; }
__device__ __forceinline__ v2f pack(float a, float b) { v2f r; r.x = a; r.y = b; return r; }

__device__ __forceinline__ float4 qnorm_fast(const float4 q) {
    float inv = frsq(fmaf(q.x, q.x, fmaf(q.y, q.y, fmaf(q.z, q.z, q.w * q.w))));
    return make_float4(q.x * inv, q.y * inv, q.z * inv, q.w * inv);
}

// s(w) = 0.25*acos(w)/sqrt(1-w^2) via acos(a) ~= sqrt(1-a)*t(a)  (A&S 4.4.45,
// |err|<=6.8e-5 rad), coefficients pre-scaled by 0.25. Packed over 2 points.
__device__ __forceinline__ v2f log_scale_v(v2f w) {
    v2f a = __builtin_elementwise_min(__builtin_elementwise_abs(w), vsplat(0.9999999f));
    v2f t = vfma(a, vfma(a, vfma(a, vsplat(-0.004682325f), vsplat(0.018565250f)),
                         vsplat(-0.053028600f)), vsplat(0.392682200f));
    v2f opa = vsplat(1.0f) + a;
    v2f oma = vsplat(1.0f) - a;
    v2f r1, r2;
    r1.x = frsq(opa.x); r1.y = frsq(opa.y);
    r2.x = frsq(oma.x); r2.y = frsq(oma.y);
    v2f u = vfma(vsplat(0.785398163f), r2, -t);
    v2i m = w >= vsplat(0.0f);
    v2f sel = m ? t : u;
    return r1 * sel;
}

// cos(sqrt(x)), sin(sqrt(x))/sqrt(x) for x = theta^2 in [0, pi^2], packed.
__device__ __forceinline__ v2f sinc_poly_v(v2f x) {
    v2f s = vfma(x, vsplat(1.60590438e-10f), vsplat(-2.50521084e-8f));
    s = vfma(x, s, vsplat(2.75573192e-6f));
    s = vfma(x, s, vsplat(-1.98412698e-4f));
    s = vfma(x, s, vsplat(8.33333333e-3f));
    s = vfma(x, s, vsplat(-1.66666667e-1f));
    return vfma(x, s, vsplat(1.0f));
}
__device__ __forceinline__ v2f cos_poly_v(v2f x) {
    v2f c = vfma(x, vsplat(-1.14707456e-11f), vsplat(2.08767570e-9f));
    c = vfma(x, c, vsplat(-2.75573192e-7f));
    c = vfma(x, c, vsplat(2.48015873e-5f));
    c = vfma(x, c, vsplat(-1.38888889e-3f));
    c = vfma(x, c, vsplat(4.16666667e-2f));
    c = vfma(x, c, vsplat(-0.5f));
    return vfma(x, c, vsplat(1.0f));
}

// P[k*4+c]: quaternion k, component c (c0=w). M[c]: current mean. All v2f
// over the chain's two points. Indices are static (callers fully unroll).

// Peeled first iteration: M = P0 exactly -> w0 = 1, s0 = 0.25.
__device__ __forceinline__ void chain_peel(const v2f* P, v2f* M) {
    v2f w[4], s[4];
    #pragma unroll
    for (int k = 1; k < 4; ++k)
        w[k] = vfma(P[0], P[k*4+0], vfma(P[1], P[k*4+1],
                vfma(P[2], P[k*4+2], P[3] * P[k*4+3])));
    #pragma unroll
    for (int k = 1; k < 4; ++k) s[k] = log_scale_v(w[k]);
    v2f d = vfma(s[1], w[1], vfma(s[2], w[2], vfma(s[3], w[3], vsplat(0.25f))));
    v2f nd = -d;
    v2f E[4];
    #pragma unroll
    for (int c = 0; c < 4; ++c) {
        v2f T = vfma(s[1], P[1*4+c], vfma(s[2], P[2*4+c],
                 vfma(s[3], P[3*4+c], vsplat(0.25f) * P[c])));
        E[c] = vfma(nd, P[c], T);
    }
    v2f x = vfma(E[0], E[0], vfma(E[1], E[1], vfma(E[2], E[2], E[3] * E[3])));
    v2f sc = sinc_poly_v(x), cc = cos_poly_v(x);
    #pragma unroll
    for (int c = 0; c < 4; ++c) M[c] = vfma(cc, P[c], sc * E[c]);
}

__device__ __forceinline__ void chain_iter(const v2f* P, v2f* M) {
    v2f w[4], s[4];
    #pragma unroll
    for (int k = 0; k < 4; ++k)
        w[k] = vfma(M[0], P[k*4+0], vfma(M[1], P[k*4+1],
                vfma(M[2], P[k*4+2], M[3] * P[k*4+3])));
    #pragma unroll
    for (int k = 0; k < 4; ++k) s[k] = log_scale_v(w[k]);
    v2f d = vfma(s[0], w[0], vfma(s[1], w[1], vfma(s[2], w[2], s[3] * w[3])));
    v2f nd = -d;
    v2f E[4];
    #pragma unroll
    for (int c = 0; c < 4; ++c) {
        v2f T = vfma(s[0], P[c], vfma(s[1], P[1*4+c],
                 vfma(s[2], P[2*4+c], s[3] * P[3*4+c])));
        E[c] = vfma(nd, M[c], T);
    }
    v2f x = vfma(E[0], E[0], vfma(E[1], E[1], vfma(E[2], E[2], E[3] * E[3])));
    v2f sc = sinc_poly_v(x), cc = cos_poly_v(x);
    #pragma unroll
    for (int c = 0; c < 4; ++c) M[c] = vfma(cc, M[c], sc * E[c]);
}

__global__ __launch_bounds__(256) void karcher_kernel(
    const float4* __restrict__ aud, const float4* __restrict__ vis,
    const float4* __restrict__ txt, const float4* __restrict__ gen,
    float* __restrict__ out, float* __restrict__ ws)
{
    const int tid = blockIdx.x * 256 + threadIdx.x;
    const int i0  = tid * 4;          // 4 points/thread = 2 packed chains

    v2f P[2][16], M[2][4];

    #pragma unroll
    for (int ch = 0; ch < 2; ++ch) {
        const int b = i0 + 2 * ch;
        float4 qa, qb;
        qa = qnorm_fast(aud[b]); qb = qnorm_fast(aud[b + 1]);
        P[ch][0]  = pack(qa.x, qb.x); P[ch][1]  = pack(qa.y, qb.y);
        P[ch][2]  = pack(qa.z, qb.z); P[ch][3]  = pack(qa.w, qb.w);
        qa = qnorm_fast(vis[b]); qb = qnorm_fast(vis[b + 1]);
        P[ch][4]  = pack(qa.x, qb.x); P[ch][5]  = pack(qa.y, qb.y);
        P[ch][6]  = pack(qa.z, qb.z); P[ch][7]  = pack(qa.w, qb.w);
        qa = qnorm_fast(txt[b]); qb = qnorm_fast(txt[b + 1]);
        P[ch][8]  = pack(qa.x, qb.x); P[ch][9]  = pack(qa.y, qb.y);
        P[ch][10] = pack(qa.z, qb.z); P[ch][11] = pack(qa.w, qb.w);
        qa = qnorm_fast(gen[b]); qb = qnorm_fast(gen[b + 1]);
        P[ch][12] = pack(qa.x, qb.x); P[ch][13] = pack(qa.y, qb.y);
        P[ch][14] = pack(qa.z, qb.z); P[ch][15] = pack(qa.w, qb.w);
    }

    chain_peel(P[0], M[0]);
    chain_peel(P[1], M[1]);

    // Iterations 2..10, rolled (constants hoisted); two independent packed
    // chains inside one loop body for ILP.
    #pragma unroll 1
    for (int it = 0; it < 9; ++it) {
        chain_iter(P[0], M[0]);
        chain_iter(P[1], M[1]);
    }

    float ss = 0.0f;
    #pragma unroll
    for (int ch = 0; ch < 2; ++ch) {
        v2f* m = M[ch];
        // final normalize (reference normalizes the returned barycenter)
        v2f nn = vfma(m[0], m[0], vfma(m[1], m[1], vfma(m[2], m[2], m[3] * m[3])));
        v2f inv; inv.x = frsq(nn.x); inv.y = frsq(nn.y);
        #pragma unroll
        for (int c = 0; c < 4; ++c) m[c] = m[c] * inv;

        float4 oa = make_float4(m[0].x, m[1].x, m[2].x, m[3].x);
        float4 ob = make_float4(m[0].y, m[1].y, m[2].y, m[3].y);
        reinterpret_cast<float4*>(out)[i0 + 2 * ch]     = oa;
        reinterpret_cast<float4*>(out)[i0 + 2 * ch + 1] = ob;

        // curvature contribution |m - m/(|m|+1e-12)|^2 (both lanes)
        v2f nn2 = vfma(m[0], m[0], vfma(m[1], m[1], vfma(m[2], m[2], m[3] * m[3])));
        v2f invn; invn.x = frcp(fsqrt(nn2.x) + 1e-12f);
                  invn.y = frcp(fsqrt(nn2.y) + 1e-12f);
        v2f nim = -invn;
        v2f ssv = vsplat(0.0f);
        #pragma unroll
        for (int c = 0; c < 4; ++c) {
            v2f e = vfma(nim, m[c], m[c]);
            ssv = vfma(e, e, ssv);
        }
        ss += ssv.x + ssv.y;
    }

    // Output 1: eta = angle(det_s)/pi. det_s imag parts are (a*b - a*b) == 0
    // exactly in fp32; real part = |q|^2 > 0  =>  angle == 0 exactly.
    reinterpret_cast<float4*>(out + 4 * NPTS)[tid] = make_float4(0.f, 0.f, 0.f, 0.f);

    // wave(64) shfl reduce -> LDS across the 4 waves -> one plain store/block
    #pragma unroll
    for (int off = 32; off > 0; off >>= 1)
        ss += __shfl_down(ss, off, 64);
    __shared__ float part[4];
    if ((threadIdx.x & 63) == 0) part[threadIdx.x >> 6] = ss;
    __syncthreads();
    if (threadIdx.x == 0)
        ws[blockIdx.x] = part[0] + part[1] + part[2] + part[3];
}

__global__ __launch_bounds__(256) void finish_kernel(
    const float* __restrict__ ws, float* __restrict__ out)
{
    float s = 0.0f;
    #pragma unroll 4
    for (int k = threadIdx.x; k < NBLK; k += 256)
        s += ws[k];
    #pragma unroll
    for (int off = 32; off > 0; off >>= 1)
        s += __shfl_down(s, off, 64);
    __shared__ float part[4];
    if ((threadIdx.x & 63) == 0) part[threadIdx.x >> 6] = s;
    __syncthreads();
    if (threadIdx.x == 0)
        out[5 * NPTS] = 1.0f / (1.0f + sqrtf(part[0] + part[1] + part[2] + part[3]));
}

extern "C" void kernel_launch(void* const* d_in, const int* in_sizes, int n_in,
                              void* d_out, int out_size, void* d_ws, size_t ws_size,
                              hipStream_t stream) {
    const float4* aud = (const float4*)d_in[0];
    const float4* vis = (const float4*)d_in[1];
    const float4* txt = (const float4*)d_in[2];
    const float4* gen = (const float4*)d_in[3];
    float* out = (float*)d_out;
    float* ws = (float*)d_ws;   // NBLK floats, fully overwritten every call

    karcher_kernel<<<NBLK, 256, 0, stream>>>(aud, vis, txt, gen, out, ws);
    finish_kernel<<<1, 256, 0, stream>>>(ws, out);
}